// Round 13
// baseline (4715.374 us; speedup 1.0000x reference)
//
#include <hip/hip_runtime.h>

#define TDIM 16

// repack OIHW (fp32) -> [ic*K*K][oc]
template<int OC>
__global__ __launch_bounds__(256) void repack_k(const float* __restrict__ w,
                                                float* __restrict__ wT, int tot) {
  int i = blockIdx.x * 256 + threadIdx.x;
  if (i >= tot) return;
  int row = i / OC, oc = i - row * OC;          // row = ic*K*K + ky*K + kx
  wT[i] = w[(size_t)oc * (size_t)(tot / OC) + row];
}

// e2[r] = sum_f32 e*e
__global__ __launch_bounds__(256) void e2_k(const float* __restrict__ emb,
                                            float* __restrict__ e2) {
  int r = blockIdx.x * 256 + threadIdx.x;
  if (r >= 512) return;
  float s = 0.f;
#pragma unroll
  for (int d = 0; d < 64; ++d) s = fmaf(emb[r * 64 + d], emb[r * 64 + d], s);
  e2[r] = s;
}

// Direct conv: fp32 in/out, fp32 accumulate, bias in accumulator.
// Weight layout [ic*K*K + ky*K + kx][OC].
template<int IC, int OC, int K, int S, int PAD, int CCH, int IH, int IW,
         bool RELU_IN, bool RELU_OUT>
__global__ __launch_bounds__(256) void conv_direct(
    const float* __restrict__ in, const float* __restrict__ wT,
    const float* __restrict__ bias, float* __restrict__ out) {
  constexpr int OH = (IH + 2 * PAD - K) / S + 1;
  constexpr int OW = OH;
  constexpr int RS = (TDIM - 1) * S + K;   // staged rows
  constexpr int CS = RS;                   // staged cols
  constexpr int TX = OW / TDIM;
  constexpr int TOT = CCH * RS * CS;

  __shared__ float lds[TOT];

  const int tid = threadIdx.x;
  const int n = blockIdx.y;
  const int tile = blockIdx.x;
  const int oh0 = (tile / TX) * TDIM;
  const int ow0 = (tile % TX) * TDIM;
  const int ty = tid >> 4, tx = tid & 15;
  const int oh = oh0 + ty, ow = ow0 + tx;

  float acc[OC];
#pragma unroll
  for (int oc = 0; oc < OC; ++oc) acc[oc] = bias[oc];

  for (int ic0 = 0; ic0 < IC; ic0 += CCH) {
    __syncthreads();
    for (int i = tid; i < TOT; i += 256) {
      int c = i / (RS * CS);
      int rem = i - c * (RS * CS);
      int r = rem / CS;
      int col = rem - r * CS;
      int gr = oh0 * S + r - PAD;
      int gc = ow0 * S + col - PAD;
      float v = 0.f;
      if (gr >= 0 && gr < IH && gc >= 0 && gc < IW) {
        v = in[((size_t)(n * IC + ic0 + c) * IH + gr) * IW + gc];
        if (RELU_IN) v = fmaxf(v, 0.f);
      }
      lds[i] = v;
    }
    __syncthreads();
#pragma unroll 1
    for (int c = 0; c < CCH; ++c) {
      const float* wbase = wT + (size_t)(ic0 + c) * (K * K * OC);
#pragma unroll
      for (int ky = 0; ky < K; ++ky)
#pragma unroll
        for (int kx = 0; kx < K; ++kx) {
          float v = lds[(c * RS + ty * S + ky) * CS + tx * S + kx];
          const float* w = wbase + (ky * K + kx) * OC;
#pragma unroll
          for (int oc = 0; oc < OC; ++oc) acc[oc] = fmaf(w[oc], v, acc[oc]);
        }
    }
  }

#pragma unroll
  for (int oc = 0; oc < OC; ++oc) {
    float r = acc[oc];
    if (RELU_OUT) r = fmaxf(r, 0.f);
    out[((size_t)(n * OC + oc) * OH + oh) * OW + ow] = r;
  }
}

// 1x1 conv (relu on read) + residual add, fp32; spatial = 64x64 = 4096
template<int IC, int OC>
__global__ __launch_bounds__(256) void conv1x1_res(
    const float* __restrict__ in, const float* __restrict__ wT,
    const float* __restrict__ bias, const float* __restrict__ res,
    float* __restrict__ out) {
  const int pid = blockIdx.x * 256 + threadIdx.x;
  const int n = pid >> 12, px = pid & 4095;
  const float* ip = in + (size_t)n * IC * 4096 + px;
  float acc[OC];
#pragma unroll
  for (int o = 0; o < OC; ++o) acc[o] = bias[o];
#pragma unroll 4
  for (int i = 0; i < IC; ++i) {
    float v = fmaxf(ip[(size_t)i * 4096], 0.f);
    const float* w = wT + i * OC;
#pragma unroll
    for (int o = 0; o < OC; ++o) acc[o] = fmaf(w[o], v, acc[o]);
  }
  const float* rp = res + (size_t)n * OC * 4096 + px;
  float* op = out + (size_t)n * OC * 4096 + px;
#pragma unroll
  for (int o = 0; o < OC; ++o) op[(size_t)o * 4096] = rp[(size_t)o * 4096] + acc[o];
}

// Fused: relu -> conv4 (1x1, 128->64, fp32) -> VQ distances/argmin (fp32)
// -> pure gather: copy the raw fp32 emb row verbatim, (B,H,W,D) contiguous.
__global__ __launch_bounds__(256) void conv4_vq(
    const float* __restrict__ h, const float* __restrict__ wT4,
    const float* __restrict__ b4, const float* __restrict__ emb,
    const float* __restrict__ e2, float* __restrict__ out) {
  const int pid = blockIdx.x * 256 + threadIdx.x;
  const int n = pid >> 12, px = pid & 4095;
  const float* ip = h + (size_t)n * 128 * 4096 + px;
  float z[64];
#pragma unroll
  for (int d = 0; d < 64; ++d) z[d] = b4[d];
#pragma unroll 2
  for (int i = 0; i < 128; ++i) {
    float v = fmaxf(ip[(size_t)i * 4096], 0.f);
    const float* w = wT4 + i * 64;
#pragma unroll
    for (int d = 0; d < 64; ++d) z[d] = fmaf(w[d], v, z[d]);
  }
  float z2 = 0.f;
#pragma unroll
  for (int d = 0; d < 64; ++d) z2 = fmaf(z[d], z[d], z2);

  float best = __builtin_inff();
  int bidx = 0;
#pragma unroll 1
  for (int r = 0; r < 512; ++r) {
    const float* e = emb + r * 64;
    float p0 = 0.f, p1 = 0.f, p2 = 0.f, p3 = 0.f;
#pragma unroll
    for (int d = 0; d < 64; d += 4) {
      p0 = fmaf(e[d + 0], z[d + 0], p0);
      p1 = fmaf(e[d + 1], z[d + 1], p1);
      p2 = fmaf(e[d + 2], z[d + 2], p2);
      p3 = fmaf(e[d + 3], z[d + 3], p3);
    }
    float dot = (p0 + p1) + (p2 + p3);
    float dist = (z2 - 2.f * dot) + e2[r];    // ref association order
    if (dist < best) { best = dist; bidx = r; }   // strict <, first index
  }

  // (B,H,W,D) contiguous gather: out[pid*64 + d] = emb[bidx][d], fp32 verbatim
  const float4* eb = (const float4*)(emb + (size_t)bidx * 64);
  float4* op = (float4*)(out + (size_t)pid * 64);
#pragma unroll
  for (int q = 0; q < 16; ++q) op[q] = eb[q];
}

extern "C" void kernel_launch(void* const* d_in, const int* in_sizes, int n_in,
                              void* d_out, int out_size, void* d_ws, size_t ws_size,
                              hipStream_t stream) {
  const float* x    = (const float*)d_in[0];
  const float* w1   = (const float*)d_in[1];
  const float* b1   = (const float*)d_in[2];
  const float* w2   = (const float*)d_in[3];
  const float* b2   = (const float*)d_in[4];
  const float* w3   = (const float*)d_in[5];
  const float* b3   = (const float*)d_in[6];
  const float* r1w1 = (const float*)d_in[7];
  const float* r1b1 = (const float*)d_in[8];
  const float* r1w2 = (const float*)d_in[9];
  const float* r1b2 = (const float*)d_in[10];
  const float* r2w1 = (const float*)d_in[11];
  const float* r2b1 = (const float*)d_in[12];
  const float* r2w2 = (const float*)d_in[13];
  const float* r2b2 = (const float*)d_in[14];
  const float* w4   = (const float*)d_in[15];
  const float* b4   = (const float*)d_in[16];
  const float* emb  = (const float*)d_in[17];

  // ---- workspace: f32 weights up front, f32 activations per batch chunk ----
  char* ws = (char*)d_ws;
  float* wT1   = (float*)ws;         // 1024
  float* wT2   = wT1 + 1024;         // 131072
  float* wT3   = wT2 + 131072;       // 147456
  float* wTr1a = wT3 + 147456;       // 36864
  float* wTr1b = wTr1a + 36864;      // 4096
  float* wTr2a = wTr1b + 4096;       // 36864
  float* wTr2b = wTr2a + 36864;      // 4096
  float* wT4   = wTr2b + 4096;       // 8192
  float* e2v   = wT4 + 8192;         // 512

  const size_t WOFF = 2ull << 20;                  // 2 MiB for weights
  const size_t SZ_A = 4194304ull;    // per-image: 64ch*128*128*4 (h1/h3/h5)
  const size_t SZ_B = 2097152ull;    // per-image: 128ch*64*64*4  (h2/h4)
  const size_t SZ_C = 524288ull;     // per-image: 32ch*64*64*4   (t32)
  const size_t PER_IMG = SZ_A + SZ_B + SZ_C;       // 6.5 MiB
  int NB = 64;
  while (NB > 1 && WOFF + (size_t)NB * PER_IMG > ws_size) NB >>= 1;

  char* bufs = ws + WOFF;
  float* A  = (float*)bufs;
  float* B_ = (float*)(bufs + (size_t)NB * SZ_A);
  float* C_ = (float*)(bufs + (size_t)NB * (SZ_A + SZ_B));

  auto blk = [](int tot) { return (tot + 255) / 256; };
  repack_k<64> <<<blk(1024),   256, 0, stream>>>(w1,   wT1,   1024);
  repack_k<128><<<blk(131072), 256, 0, stream>>>(w2,   wT2,   131072);
  repack_k<128><<<blk(147456), 256, 0, stream>>>(w3,   wT3,   147456);
  repack_k<32> <<<blk(36864),  256, 0, stream>>>(r1w1, wTr1a, 36864);
  repack_k<128><<<blk(4096),   256, 0, stream>>>(r1w2, wTr1b, 4096);
  repack_k<32> <<<blk(36864),  256, 0, stream>>>(r2w1, wTr2a, 36864);
  repack_k<128><<<blk(4096),   256, 0, stream>>>(r2w2, wTr2b, 4096);
  repack_k<64> <<<blk(8192),   256, 0, stream>>>(w4,   wT4,   8192);
  e2_k<<<2, 256, 0, stream>>>(emb, e2v);

  for (int n0 = 0; n0 < 64; n0 += NB) {
    const int nb = (64 - n0 < NB) ? (64 - n0) : NB;
    const float* xc = x + (size_t)n0 * 65536;               // (nb,1,256,256)
    float* oc = (float*)d_out + (size_t)n0 * 4096 * 64;     // BHWD chunk base

    // conv1: (nb,1,256,256) -> relu -> h1 (nb,64,128,128)
    conv_direct<1, 64, 4, 2, 1, 1, 256, 256, false, true>
        <<<dim3(64, nb), 256, 0, stream>>>(xc, wT1, b1, A);
    // conv2: h1 -> relu -> h2 (nb,128,64,64)
    conv_direct<64, 128, 4, 2, 1, 4, 128, 128, false, true>
        <<<dim3(16, nb), 256, 0, stream>>>(A, wT2, b2, B_);
    // conv3: h2 -> h3 (nb,128,64,64)
    conv_direct<128, 128, 3, 1, 1, 8, 64, 64, false, false>
        <<<dim3(16, nb), 256, 0, stream>>>(B_, wT3, b3, A);
    // res1: t32 = conv3x3(relu(h3)) ; h4 = h3 + conv1x1(relu(t32))
    conv_direct<128, 32, 3, 1, 1, 8, 64, 64, true, false>
        <<<dim3(16, nb), 256, 0, stream>>>(A, wTr1a, r1b1, C_);
    conv1x1_res<32, 128><<<nb * 16, 256, 0, stream>>>(C_, wTr1b, r1b2, A, B_);
    // res2: t32 = conv3x3(relu(h4)) ; h5 = h4 + conv1x1(relu(t32))
    conv_direct<128, 32, 3, 1, 1, 8, 64, 64, true, false>
        <<<dim3(16, nb), 256, 0, stream>>>(B_, wTr2a, r2b1, C_);
    conv1x1_res<32, 128><<<nb * 16, 256, 0, stream>>>(C_, wTr2b, r2b2, B_, A);
    // conv4 + VQ: relu(h5) -> z (fp32) -> fp32 distances -> argmin
    //  -> gather raw fp32 emb row, (B,H,W,D) contiguous
    conv4_vq<<<nb * 16, 256, 0, stream>>>(A, wT4, b4, emb, e2v, oc);
  }
}

// Round 14
// 4206.501 us; speedup vs baseline: 1.1210x; 1.1210x over previous
//
#include <hip/hip_runtime.h>

#define TDIM 16

// repack OIHW (fp32) -> [ic*K*K][oc]
template<int OC>
__global__ __launch_bounds__(256) void repack_k(const float* __restrict__ w,
                                                float* __restrict__ wT, int tot) {
  int i = blockIdx.x * 256 + threadIdx.x;
  if (i >= tot) return;
  int row = i / OC, oc = i - row * OC;          // row = ic*K*K + ky*K + kx
  wT[i] = w[(size_t)oc * (size_t)(tot / OC) + row];
}

// e2[r] = sum_f32 e*e
__global__ __launch_bounds__(256) void e2_k(const float* __restrict__ emb,
                                            float* __restrict__ e2) {
  int r = blockIdx.x * 256 + threadIdx.x;
  if (r >= 512) return;
  float s = 0.f;
#pragma unroll
  for (int d = 0; d < 64; ++d) s = fmaf(emb[r * 64 + d], emb[r * 64 + d], s);
  e2[r] = s;
}

// Direct conv: fp32, bias in accumulator. Weights staged in LDS per ic-chunk
// (uniform float4 broadcast reads — removes scalar-load latency stalls).
// Weight layout [ic*K*K + ky*K + kx][OC].
template<int IC, int OC, int K, int S, int PAD, int CCH, int IH, int IW,
         bool RELU_IN, bool RELU_OUT>
__global__ __launch_bounds__(256) void conv_direct(
    const float* __restrict__ in, const float* __restrict__ wT,
    const float* __restrict__ bias, float* __restrict__ out) {
  constexpr int OH = (IH + 2 * PAD - K) / S + 1;
  constexpr int OW = OH;
  constexpr int RS = (TDIM - 1) * S + K;   // staged rows
  constexpr int CS = RS;                   // staged cols
  constexpr int TX = OW / TDIM;
  constexpr int TOT = CCH * RS * CS;
  constexpr int WSLAB = CCH * K * K * OC;  // weights per ic chunk

  __shared__ __align__(16) float lds[TOT];
  __shared__ __align__(16) float wlds[WSLAB];

  const int tid = threadIdx.x;
  const int n = blockIdx.y;
  const int tile = blockIdx.x;
  const int oh0 = (tile / TX) * TDIM;
  const int ow0 = (tile % TX) * TDIM;
  const int ty = tid >> 4, tx = tid & 15;
  const int oh = oh0 + ty, ow = ow0 + tx;

  float acc[OC];
#pragma unroll
  for (int oc = 0; oc < OC; ++oc) acc[oc] = bias[oc];

  for (int ic0 = 0; ic0 < IC; ic0 += CCH) {
    __syncthreads();
    // stage input tile
    for (int i = tid; i < TOT; i += 256) {
      int c = i / (RS * CS);
      int rem = i - c * (RS * CS);
      int r = rem / CS;
      int col = rem - r * CS;
      int gr = oh0 * S + r - PAD;
      int gc = ow0 * S + col - PAD;
      float v = 0.f;
      if (gr >= 0 && gr < IH && gc >= 0 && gc < IW) {
        v = in[((size_t)(n * IC + ic0 + c) * IH + gr) * IW + gc];
        if (RELU_IN) v = fmaxf(v, 0.f);
      }
      lds[i] = v;
    }
    // stage weight slab (contiguous in wT)
    {
      const float* wsrc = wT + (size_t)ic0 * (K * K * OC);
      for (int i = tid; i < WSLAB; i += 256) wlds[i] = wsrc[i];
    }
    __syncthreads();
#pragma unroll 1
    for (int c = 0; c < CCH; ++c) {
#pragma unroll
      for (int ky = 0; ky < K; ++ky)
#pragma unroll
        for (int kx = 0; kx < K; ++kx) {
          float v = lds[(c * RS + ty * S + ky) * CS + tx * S + kx];
          const float4* w4 =
              (const float4*)(wlds + (c * K * K + ky * K + kx) * OC);
#pragma unroll
          for (int q = 0; q < OC / 4; ++q) {
            float4 wv = w4[q];
            acc[4 * q + 0] = fmaf(wv.x, v, acc[4 * q + 0]);
            acc[4 * q + 1] = fmaf(wv.y, v, acc[4 * q + 1]);
            acc[4 * q + 2] = fmaf(wv.z, v, acc[4 * q + 2]);
            acc[4 * q + 3] = fmaf(wv.w, v, acc[4 * q + 3]);
          }
        }
    }
  }

#pragma unroll
  for (int oc = 0; oc < OC; ++oc) {
    float r = acc[oc];
    if (RELU_OUT) r = fmaxf(r, 0.f);
    out[((size_t)(n * OC + oc) * OH + oh) * OW + ow] = r;
  }
}

// 1x1 conv (relu on read) + residual add, fp32; weights staged in LDS.
template<int IC, int OC>
__global__ __launch_bounds__(256) void conv1x1_res(
    const float* __restrict__ in, const float* __restrict__ wT,
    const float* __restrict__ bias, const float* __restrict__ res,
    float* __restrict__ out) {
  __shared__ __align__(16) float wlds[IC * OC];
  for (int i = threadIdx.x; i < IC * OC; i += 256) wlds[i] = wT[i];
  __syncthreads();

  const int pid = blockIdx.x * 256 + threadIdx.x;
  const int n = pid >> 12, px = pid & 4095;
  const float* ip = in + (size_t)n * IC * 4096 + px;
  float acc[OC];
#pragma unroll
  for (int o = 0; o < OC; ++o) acc[o] = bias[o];
#pragma unroll 4
  for (int i = 0; i < IC; ++i) {
    float v = fmaxf(ip[(size_t)i * 4096], 0.f);
    const float4* w4 = (const float4*)(wlds + i * OC);
#pragma unroll
    for (int q = 0; q < OC / 4; ++q) {
      float4 wv = w4[q];
      acc[4 * q + 0] = fmaf(wv.x, v, acc[4 * q + 0]);
      acc[4 * q + 1] = fmaf(wv.y, v, acc[4 * q + 1]);
      acc[4 * q + 2] = fmaf(wv.z, v, acc[4 * q + 2]);
      acc[4 * q + 3] = fmaf(wv.w, v, acc[4 * q + 3]);
    }
  }
  const float* rp = res + (size_t)n * OC * 4096 + px;
  float* op = out + (size_t)n * OC * 4096 + px;
#pragma unroll
  for (int o = 0; o < OC; ++o) op[(size_t)o * 4096] = rp[(size_t)o * 4096] + acc[o];
}

// Fused: relu -> conv4 (1x1, 128->64) -> VQ distances/argmin (fp32)
// -> gather raw fp32 emb row, (B,H,W,D) contiguous.
// wT4 (32KB), e2 (2KB) staged once; emb staged in 64-row chunks (16KB).
__global__ __launch_bounds__(256) void conv4_vq(
    const float* __restrict__ h, const float* __restrict__ wT4,
    const float* __restrict__ b4, const float* __restrict__ emb,
    const float* __restrict__ e2, float* __restrict__ out) {
  __shared__ __align__(16) float wlds[128 * 64];   // 32 KB
  __shared__ __align__(16) float elds[64 * 64];    // 16 KB
  __shared__ float e2lds[512];                     // 2 KB

  const int tid = threadIdx.x;
  for (int i = tid; i < 128 * 64; i += 256) wlds[i] = wT4[i];
  for (int i = tid; i < 512; i += 256) e2lds[i] = e2[i];
  __syncthreads();

  const int pid = blockIdx.x * 256 + tid;
  const int n = pid >> 12, px = pid & 4095;
  const float* ip = h + (size_t)n * 128 * 4096 + px;
  float z[64];
#pragma unroll
  for (int d = 0; d < 64; ++d) z[d] = b4[d];
#pragma unroll 2
  for (int i = 0; i < 128; ++i) {
    float v = fmaxf(ip[(size_t)i * 4096], 0.f);
    const float4* w4 = (const float4*)(wlds + i * 64);
#pragma unroll
    for (int q = 0; q < 16; ++q) {
      float4 wv = w4[q];
      z[4 * q + 0] = fmaf(wv.x, v, z[4 * q + 0]);
      z[4 * q + 1] = fmaf(wv.y, v, z[4 * q + 1]);
      z[4 * q + 2] = fmaf(wv.z, v, z[4 * q + 2]);
      z[4 * q + 3] = fmaf(wv.w, v, z[4 * q + 3]);
    }
  }
  float z2 = 0.f;
#pragma unroll
  for (int d = 0; d < 64; ++d) z2 = fmaf(z[d], z[d], z2);

  float best = __builtin_inff();
  int bidx = 0;
  for (int r0 = 0; r0 < 512; r0 += 64) {
    __syncthreads();
    for (int i = tid; i < 64 * 64; i += 256) elds[i] = emb[(size_t)r0 * 64 + i];
    __syncthreads();
#pragma unroll 1
    for (int r = 0; r < 64; ++r) {
      const float4* e4 = (const float4*)(elds + r * 64);
      float p0 = 0.f, p1 = 0.f, p2 = 0.f, p3 = 0.f;
#pragma unroll
      for (int q = 0; q < 16; ++q) {
        float4 ev = e4[q];
        p0 = fmaf(ev.x, z[4 * q + 0], p0);
        p1 = fmaf(ev.y, z[4 * q + 1], p1);
        p2 = fmaf(ev.z, z[4 * q + 2], p2);
        p3 = fmaf(ev.w, z[4 * q + 3], p3);
      }
      float dot = (p0 + p1) + (p2 + p3);
      float dist = (z2 - 2.f * dot) + e2lds[r0 + r];  // ref association order
      if (dist < best) { best = dist; bidx = r0 + r; }  // strict <, 1st index
    }
  }

  // (B,H,W,D) contiguous gather: out[pid*64 + d] = emb[bidx][d], fp32 verbatim
  const float4* eb = (const float4*)(emb + (size_t)bidx * 64);
  float4* op = (float4*)(out + (size_t)pid * 64);
#pragma unroll
  for (int q = 0; q < 16; ++q) op[q] = eb[q];
}

extern "C" void kernel_launch(void* const* d_in, const int* in_sizes, int n_in,
                              void* d_out, int out_size, void* d_ws, size_t ws_size,
                              hipStream_t stream) {
  const float* x    = (const float*)d_in[0];
  const float* w1   = (const float*)d_in[1];
  const float* b1   = (const float*)d_in[2];
  const float* w2   = (const float*)d_in[3];
  const float* b2   = (const float*)d_in[4];
  const float* w3   = (const float*)d_in[5];
  const float* b3   = (const float*)d_in[6];
  const float* r1w1 = (const float*)d_in[7];
  const float* r1b1 = (const float*)d_in[8];
  const float* r1w2 = (const float*)d_in[9];
  const float* r1b2 = (const float*)d_in[10];
  const float* r2w1 = (const float*)d_in[11];
  const float* r2b1 = (const float*)d_in[12];
  const float* r2w2 = (const float*)d_in[13];
  const float* r2b2 = (const float*)d_in[14];
  const float* w4   = (const float*)d_in[15];
  const float* b4   = (const float*)d_in[16];
  const float* emb  = (const float*)d_in[17];

  // ---- workspace: f32 weights up front, f32 activations per batch chunk ----
  char* ws = (char*)d_ws;
  float* wT1   = (float*)ws;         // 1024
  float* wT2   = wT1 + 1024;         // 131072
  float* wT3   = wT2 + 131072;       // 147456
  float* wTr1a = wT3 + 147456;       // 36864
  float* wTr1b = wTr1a + 36864;      // 4096
  float* wTr2a = wTr1b + 4096;       // 36864
  float* wTr2b = wTr2a + 36864;      // 4096
  float* wT4   = wTr2b + 4096;       // 8192
  float* e2v   = wT4 + 8192;         // 512

  const size_t WOFF = 2ull << 20;                  // 2 MiB for weights
  const size_t SZ_A = 4194304ull;    // per-image: 64ch*128*128*4 (h1/h3/h5)
  const size_t SZ_B = 2097152ull;    // per-image: 128ch*64*64*4  (h2/h4)
  const size_t SZ_C = 524288ull;     // per-image: 32ch*64*64*4   (t32)
  const size_t PER_IMG = SZ_A + SZ_B + SZ_C;       // 6.5 MiB
  int NB = 64;
  while (NB > 1 && WOFF + (size_t)NB * PER_IMG > ws_size) NB >>= 1;

  char* bufs = ws + WOFF;
  float* A  = (float*)bufs;
  float* B_ = (float*)(bufs + (size_t)NB * SZ_A);
  float* C_ = (float*)(bufs + (size_t)NB * (SZ_A + SZ_B));

  auto blk = [](int tot) { return (tot + 255) / 256; };
  repack_k<64> <<<blk(1024),   256, 0, stream>>>(w1,   wT1,   1024);
  repack_k<128><<<blk(131072), 256, 0, stream>>>(w2,   wT2,   131072);
  repack_k<128><<<blk(147456), 256, 0, stream>>>(w3,   wT3,   147456);
  repack_k<32> <<<blk(36864),  256, 0, stream>>>(r1w1, wTr1a, 36864);
  repack_k<128><<<blk(4096),   256, 0, stream>>>(r1w2, wTr1b, 4096);
  repack_k<32> <<<blk(36864),  256, 0, stream>>>(r2w1, wTr2a, 36864);
  repack_k<128><<<blk(4096),   256, 0, stream>>>(r2w2, wTr2b, 4096);
  repack_k<64> <<<blk(8192),   256, 0, stream>>>(w4,   wT4,   8192);
  e2_k<<<2, 256, 0, stream>>>(emb, e2v);

  for (int n0 = 0; n0 < 64; n0 += NB) {
    const int nb = (64 - n0 < NB) ? (64 - n0) : NB;
    const float* xc = x + (size_t)n0 * 65536;               // (nb,1,256,256)
    float* oc = (float*)d_out + (size_t)n0 * 4096 * 64;     // BHWD chunk base

    // conv1: (nb,1,256,256) -> relu -> h1 (nb,64,128,128)
    conv_direct<1, 64, 4, 2, 1, 1, 256, 256, false, true>
        <<<dim3(64, nb), 256, 0, stream>>>(xc, wT1, b1, A);
    // conv2: h1 -> relu -> h2 (nb,128,64,64)
    conv_direct<64, 128, 4, 2, 1, 4, 128, 128, false, true>
        <<<dim3(16, nb), 256, 0, stream>>>(A, wT2, b2, B_);
    // conv3: h2 -> h3 (nb,128,64,64)
    conv_direct<128, 128, 3, 1, 1, 8, 64, 64, false, false>
        <<<dim3(16, nb), 256, 0, stream>>>(B_, wT3, b3, A);
    // res1: t32 = conv3x3(relu(h3)) ; h4 = h3 + conv1x1(relu(t32))
    conv_direct<128, 32, 3, 1, 1, 8, 64, 64, true, false>
        <<<dim3(16, nb), 256, 0, stream>>>(A, wTr1a, r1b1, C_);
    conv1x1_res<32, 128><<<nb * 16, 256, 0, stream>>>(C_, wTr1b, r1b2, A, B_);
    // res2: t32 = conv3x3(relu(h4)) ; h5 = h4 + conv1x1(relu(t32))
    conv_direct<128, 32, 3, 1, 1, 8, 64, 64, true, false>
        <<<dim3(16, nb), 256, 0, stream>>>(B_, wTr2a, r2b1, C_);
    conv1x1_res<32, 128><<<nb * 16, 256, 0, stream>>>(C_, wTr2b, r2b2, B_, A);
    // conv4 + VQ: relu(h5) -> z (fp32) -> fp32 distances -> argmin
    //  -> gather raw fp32 emb row, (B,H,W,D) contiguous
    conv4_vq<<<nb * 16, 256, 0, stream>>>(A, wT4, b4, emb, e2v, oc);
  }
}